// Round 3
// baseline (378.775 us; speedup 1.0000x reference)
//
#include <hip/hip_runtime.h>
#include <math.h>

#define DI static __device__ __forceinline__

DI float eluf(float x){ return x > 0.f ? x : expm1f(x); }
DI float lreluf(float x){ return x > 0.f ? x : 0.2f*x; }
DI float sigmf(float x){ return 1.f/(1.f+expf(-x)); }

typedef unsigned short u16;
typedef unsigned int   u32;
typedef __attribute__((ext_vector_type(8))) short short8_t;
typedef __attribute__((ext_vector_type(4))) float f32x4;

DI u16 bf16rne(float f){
  u32 u = __float_as_uint(f);
  u += 0x7fffu + ((u>>16)&1u);
  return (u16)(u>>16);
}

DI f32x4 bmfma(short8_t a, short8_t b, f32x4 c){
  return __builtin_amdgcn_mfma_f32_16x16x32_bf16(a, b, c, 0, 0, 0);
}

constexpr int N=200, E=3200, HID=64, NH=16, OUTD=128, CAT=2048, SEQD=2240;

// ---- per-graph f32 scratch offsets (in floats) ----
constexpr int OH0   = 0;
constexpr int OWH   = OH0 + N*HID;
constexpr int OASN  = OWH + NH*N*OUTD;
constexpr int OADN  = OASN + NH*N;
constexpr int OH1   = OADN + NH*N;
constexpr int OXW1  = OH1 + N*CAT;
constexpr int OXW2  = OXW1 + 256;
constexpr int OEW1  = OXW2 + 256;
constexpr int OS1   = OEW1 + E;
constexpr int ODEG1 = OS1 + E;
constexpr int OSS1  = ODEG1 + 256;   // = ODEG1+256 (inline ns relies on this)
constexpr int ORAW1 = OSS1 + 256;
constexpr int OWH2  = ORAW1 + 256;
constexpr int OAS2  = OWH2 + N*OUTD;
constexpr int OAD2  = OAS2 + 256;
constexpr int OEWV  = OAD2 + 256;
constexpr int OH2B  = OEWV + E;
constexpr int OXS2  = OH2B + N*OUTD;
constexpr int OXD2  = OXS2 + 256;
constexpr int ODEG2 = OXD2 + 256;
constexpr int OSS2  = ODEG2 + 256;   // = ODEG2+256
constexpr int ORAW2 = OSS2 + 256;
constexpr int ORAW3 = ORAW2 + 256;
constexpr int PGF   = ORAW3 + 256;
constexpr int GLOBF = 10624;
constexpr int TOTF  = GLOBF + 2*PGF;

// ---- static device scratch ----
__device__ __attribute__((aligned(16))) float G_F[TOTF];
__device__ float G_E2PART[(size_t)8*2*E*OUTD];    // ew2full partials [hg=8][g][e][128]
__device__ float G_EDOTH[2*NH*E];
__device__ float G_WHHT[2*2*128*512];
__device__ int   G_PIDX[2*N*N];
__device__ __attribute__((aligned(16))) u16 G_WGAT_T[NH*OUTD*HID];  // [h][o][c] bf16
__device__ __attribute__((aligned(16))) u16 G_WOUT_T[OUTD*CAT];     // [n][q] bf16
__device__ __attribute__((aligned(16))) u16 G_EATTR_BF[2*E*HID];    // [g][e][c] bf16

DI float* gf(int g){ return G_F + GLOBF + (size_t)g*PGF; }
DI float* gv_e(){ return G_F + 1024; }
DI float* gy0(){ return G_F + 3072; }
DI float* gy1(){ return G_F + 3584; }
DI float* gxseq(){ return G_F + 4096; }
DI float* gxg(){ return G_F + 8576; }
DI int*   gpidx(int g){ return G_PIDX + g*N*N; }

struct GraphIn {
  const float *feat, *eattr, *adj, *n2n;
  const int   *eidx;
};

struct Params {
  GraphIn g[2];
  const float *W_h, *W_gat, *a_src, *a_dst, *a_e, *We_gat;
  const float *W_out, *ao_src, *ao_dst, *ao_e, *We_out;
  const float *ep1_w, *ep1_b, *ep2_w, *ep2_b;
  const float *g1_w, *g1_b, *g2_w, *g2_b, *g3_w, *g3_b;
  const float *Wih0, *Whh0, *b0, *Wih1, *Whh1, *b1, *fc_w, *fc_b;
  float *out;
};

// ---- fused init: zero atomics+EDOTH, pidx, Whh^T, gv_e, h0+g1dot, bf16 converts ----
constexpr int ZPG  = 2*E + 1024 + NH*E;       // per-graph floats to zero (incl EDOTH)
constexpr int IB_Z = (2*ZPG+255)/256;
constexpr int IB_C = (2*N*N+255)/256;
constexpr int IB_D = (2*2*512*128)/256;
constexpr int IB_E = (CAT+3)/4;
constexpr int IB_H = (2*N+3)/4;
constexpr int IB_W1 = (NH*OUTD*HID)/256;      // 512
constexpr int IB_W2 = (OUTD*CAT)/256;         // 1024
constexpr int IB_EA = (2*E*HID)/256;          // 1600
__global__ void k_init(Params P){
  int b = blockIdx.x, tid = threadIdx.x;
  if (b < IB_Z){
    int i = b*256 + tid;
    if (i < 2*ZPG){
      int g = i/ZPG, r = i%ZPG;
      if (r < 2*E+1024){
        int addr = r<E ? OEW1+r : (r<2*E ? OEWV+(r-E) :
                   (r<2*E+512 ? ODEG1+(r-2*E) : ODEG2+(r-2*E-512)));
        gf(g)[addr] = 0.f;
      } else {
        G_EDOTH[(size_t)g*NH*E + (r - (2*E+1024))] = 0.f;
      }
    }
  } else if (b < IB_Z+IB_C){
    int i = (b-IB_Z)*256 + tid; if (i < 2*N*N) G_PIDX[i] = -1;
  } else if (b < IB_Z+IB_C+IB_D){
    int idx = (b-IB_Z-IB_C)*256 + tid;
    int l = idx >> 17;
    int r = idx & 131071;
    int d = r >> 16;
    int r2 = r & 65535;
    int gate = r2 & 511;
    int k = r2 >> 9;
    const float* Whh = l ? P.Whh1 : P.Whh0;
    G_WHHT[idx] = Whh[((size_t)d*512+gate)*128 + k];
  } else if (b < IB_Z+IB_C+IB_D+IB_E){
    int gid = (b-IB_Z-IB_C-IB_D)*4 + (tid>>6);
    int lane = tid & 63;
    if (gid < CAT){
      const float* W = P.We_out + (size_t)gid*OUTD;
      float acc = 0.f;
      for (int o=lane;o<OUTD;o+=64) acc += W[o]*P.ao_e[o];
      for (int off=32;off>0;off>>=1) acc += __shfl_down(acc,off);
      if (lane==0) gv_e()[gid] = acc;
    }
  } else if (b < IB_Z+IB_C+IB_D+IB_E+IB_H){
    int unit = (b-IB_Z-IB_C-IB_D-IB_E)*4 + (tid>>6);
    if (unit >= 2*N) return;
    int g = unit / N, n = unit % N, c = tid & 63;
    const float* feat = P.g[g].feat;
    float acc = 0.f;
    for (int k=0;k<HID;k++) acc += feat[n*HID+k]*P.W_h[k*HID+c];
    float v = eluf(acc);
    float* f = gf(g);
    f[OH0 + n*HID + c] = v;
    float r = v*P.g1_w[c];
    for (int off=32;off>0;off>>=1) r += __shfl_down(r,off);
    if (c==0) f[ORAW1+n] = r;
  } else if (b < IB_Z+IB_C+IB_D+IB_E+IB_H+IB_W1){
    // We_gat [h][c][o] -> bf16 transposed [h][o][c]
    int i = (b-(IB_Z+IB_C+IB_D+IB_E+IB_H))*256 + tid;
    int h = i>>13, o = (i>>6)&127, c = i&63;
    G_WGAT_T[i] = bf16rne(P.We_gat[(size_t)(h*HID+c)*OUTD + o]);
  } else if (b < IB_Z+IB_C+IB_D+IB_E+IB_H+IB_W1+IB_W2){
    // We_out [q][n] -> bf16 transposed [n][q]
    int i = (b-(IB_Z+IB_C+IB_D+IB_E+IB_H+IB_W1))*256 + tid;
    int n = i>>11, q = i&2047;
    G_WOUT_T[i] = bf16rne(P.We_out[(size_t)q*OUTD + n]);
  } else {
    // eattr -> bf16 [g][e][c]
    int i = (b-(IB_Z+IB_C+IB_D+IB_E+IB_H+IB_W1+IB_W2))*256 + tid;
    int g = i >= E*HID ? 1 : 0;
    G_EATTR_BF[i] = bf16rne(P.g[g].eattr[i - g*E*HID]);
  }
}

// ---- Wh[h] = h0 @ W_gat[h] + fused asn/adn; y==NH slice does gpool1 output ----
__global__ void k_Wh(Params P){
  int n = blockIdx.x, h = blockIdx.y, g = blockIdx.z, o = threadIdx.x;
  float* f = gf(g);
  if (h == NH){
    if (n != 0) return;
    __shared__ float att[N];
    __shared__ float sb[128];
    for (int j = o; j < N; j += 128) att[j] = sigmf(f[ORAW1+j] + P.g1_b[0]);
    __syncthreads();
    float m = -3e38f;
    for (int j = o; j < N; j += 128) m = fmaxf(m, att[j]);
    sb[o] = m; __syncthreads();
    for (int s=64;s>0;s>>=1){ if (o<s) sb[o]=fmaxf(sb[o],sb[o+s]); __syncthreads(); }
    m = sb[0]; __syncthreads();
    float ss = 0.f;
    for (int j = o; j < N; j += 128){ float e = expf(att[j]-m); ss += e; }
    sb[o] = ss; __syncthreads();
    for (int s=64;s>0;s>>=1){ if (o<s) sb[o]+=sb[o+s]; __syncthreads(); }
    float inv = 1.f/sb[0]; __syncthreads();
    for (int j = o; j < N; j += 128) att[j] = expf(att[j]-m)*inv;
    __syncthreads();
    if (o < HID){
      float acc = 0.f;
      for (int j=0;j<N;j++) acc += att[j]*f[OH0 + j*HID + o];
      gxseq()[g*SEQD + o] = acc;
    }
    return;
  }
  __shared__ float hs[HID];
  __shared__ float sred[128], dred[128];
  if (o < HID) hs[o] = f[OH0 + n*HID + o];
  __syncthreads();
  const float* W = P.W_gat + (size_t)h*HID*OUTD + o;
  float acc = 0.f;
  for (int c=0;c<HID;c++) acc += hs[c]*W[(size_t)c*OUTD];
  f[OWH + ((size_t)h*N + n)*OUTD + o] = acc;
  sred[o] = acc*P.a_src[h*OUTD+o];
  dred[o] = acc*P.a_dst[h*OUTD+o];
  __syncthreads();
  for (int s=64;s>0;s>>=1){ if (o<s){ sred[o]+=sred[o+s]; dred[o]+=dred[o+s]; } __syncthreads(); }
  if (o==0){ f[OASN+h*N+n]=sred[0]; f[OADN+h*N+n]=dred[0]; }
}

// ---- GAT layer 1: 4 nodes/block ----
__global__ void k_att1(Params P){
  int nb = blockIdx.x, h = blockIdx.y, g = blockIdx.z, tid = threadIdx.x;
  int n0 = nb*4;
  __shared__ float z[4][N];
  __shared__ float red[128];
  __shared__ float sinv[4];
  float* f = gf(g);
  const float* adj = P.g[g].adj;
  const int* pidx = gpidx(g);
  const float* edoth = G_EDOTH + ((size_t)g*NH + h)*E;
  const float* adn = f + OADN + h*N;
  for (int i=0;i<4;i++){
    float asn = f[OASN + h*N + n0+i];
    for (int j = tid; j < N; j += 128){
      float a = adj[(n0+i)*N + j];
      float zz;
      if (a > 0.f){
        int p = pidx[(n0+i)*N + j];
        float ee = (p >= 0) ? edoth[p] : 0.f;
        zz = lreluf(asn + adn[j] + ee);
      } else zz = -1e9f;
      z[i][j] = zz;
    }
  }
  __syncthreads();
  for (int i=0;i<4;i++){
    float m = -3e38f;
    for (int j = tid; j < N; j += 128) m = fmaxf(m, z[i][j]);
    red[tid] = m; __syncthreads();
    for (int s=64;s>0;s>>=1){ if (tid<s) red[tid]=fmaxf(red[tid],red[tid+s]); __syncthreads(); }
    m = red[0]; __syncthreads();
    float ssum = 0.f;
    for (int j = tid; j < N; j += 128){ float e = expf(z[i][j]-m); z[i][j]=e; ssum += e; }
    red[tid] = ssum; __syncthreads();
    for (int s=64;s>0;s>>=1){ if (tid<s) red[tid]+=red[tid+s]; __syncthreads(); }
    if (tid==0) sinv[i] = 1.f/red[0];
    __syncthreads();
  }
  const float* wh = f + OWH + (size_t)h*N*OUTD;
  float a0=0.f,a1=0.f,a2=0.f,a3=0.f;
  for (int j=0;j<N;j++){
    float w = wh[(size_t)j*OUTD + tid];
    a0 += z[0][j]*w; a1 += z[1][j]*w; a2 += z[2][j]*w; a3 += z[3][j]*w;
  }
  f[OH1 + (size_t)(n0+0)*CAT + h*OUTD + tid] = eluf(a0*sinv[0]);
  f[OH1 + (size_t)(n0+1)*CAT + h*OUTD + tid] = eluf(a1*sinv[1]);
  f[OH1 + (size_t)(n0+2)*CAT + h*OUTD + tid] = eluf(a2*sinv[2]);
  f[OH1 + (size_t)(n0+3)*CAT + h*OUTD + tid] = eluf(a3*sinv[3]);
}

// ---- pool1 node dots + fused g2 raw gate dot ----
__global__ void k_xw1(Params P){
  int n = blockIdx.x, g = blockIdx.y, tid = threadIdx.x;
  __shared__ float s1b[256], s2b[256], s3b[256];
  float* f = gf(g);
  const float* x = f + OH1 + (size_t)n*CAT;
  float a1 = 0.f, a2 = 0.f, a3 = 0.f;
  for (int c = tid; c < CAT; c += 256){
    float xv = x[c];
    a1 += xv*P.ep1_w[c];
    a2 += xv*P.ep1_w[CAT+c];
    a3 += xv*P.g2_w[c];
  }
  s1b[tid]=a1; s2b[tid]=a2; s3b[tid]=a3; __syncthreads();
  for (int s=128;s>0;s>>=1){
    if (tid<s){ s1b[tid]+=s1b[tid+s]; s2b[tid]+=s2b[tid+s]; s3b[tid]+=s3b[tid+s]; }
    __syncthreads();
  }
  if (tid==0){ f[OXW1+n]=s1b[0]; f[OXW2+n]=s2b[0]; f[ORAW2+n]=s3b[0]; }
}

// ---------------- pool1 edge scores + segment sums ----------------
__global__ void k_s1(Params P){
  int e = blockIdx.x*256 + threadIdx.x, g = blockIdx.y;
  if (e >= E) return;
  float* f = gf(g);
  const int* ei = P.g[g].eidx;
  int s = ei[e], d = ei[E+e];
  float v = sigmf(f[OXW1+s] + f[OXW2+d] + f[OEW1+e] + P.ep1_b[0]);
  f[OS1+e] = v;
  atomicAdd(&f[OSS1+s], v);
  atomicAdd(&f[ODEG1+s], 1.f);
}

// ---------------- pairIdx: last edge wins ----------------
__global__ void k_pairs(Params P){
  int e = blockIdx.x*256 + threadIdx.x, g = blockIdx.y;
  if (e >= E) return;
  const int* ei = P.g[g].eidx;
  atomicMax(&gpidx(g)[ei[e]*N + ei[E+e]], e);
}

// ---- gpool output (pools 2/3): inline gate; column-tiled ----
__global__ void k_gpool_out(Params P, int xoff, int D, int odeg, int rawoff,
                            const float* b, int outoff){
  int cb = blockIdx.x, g = blockIdx.y, tid = threadIdx.x;
  __shared__ float att[N];
  __shared__ float sb[256];
  float* f = gf(g);
  for (int n = tid; n < N; n += 256){
    float sc = f[odeg+256+n]/(f[odeg+n]+1e-6f);
    att[n] = sigmf(f[rawoff+n]*sc + b[0]);
  }
  __syncthreads();
  float m = -3e38f;
  for (int n = tid; n < N; n += 256) m = fmaxf(m, att[n]);
  sb[tid] = m; __syncthreads();
  for (int s=128;s>0;s>>=1){ if (tid<s) sb[tid]=fmaxf(sb[tid],sb[tid+s]); __syncthreads(); }
  m = sb[0]; __syncthreads();
  float ss = 0.f;
  for (int n = tid; n < N; n += 256){ float e = expf(att[n]-m); ss += e; }
  sb[tid] = ss; __syncthreads();
  for (int s=128;s>0;s>>=1){ if (tid<s) sb[tid]+=sb[tid+s]; __syncthreads(); }
  float inv = 1.f/sb[0]; __syncthreads();
  for (int n = tid; n < N; n += 256){
    float sc = f[odeg+256+n]/(f[odeg+n]+1e-6f);
    att[n] = expf(att[n]-m)*inv*sc;
  }
  __syncthreads();
  int c = cb*256 + tid;
  if (c < D){
    const float* x = f + xoff;
    float acc = 0.f;
    for (int n=0;n<N;n++) acc += att[n]*x[(size_t)n*D + c];
    gxseq()[g*SEQD + outoff + c] = acc;
  }
}

// ---- Wh2 (N,2; 512 thr) + fused asad2 tail ----
__global__ void k_Wh2(Params P){
  int n = blockIdx.x, g = blockIdx.y, tid = threadIdx.x;
  int kq = tid >> 7, o = tid & 127;
  __shared__ float hrow[4][128];
  __shared__ float part[4][128];
  __shared__ float sr[128], dr[128];
  float* f = gf(g);
  const float* x = f + OH1 + (size_t)n*CAT;
  float acc = 0.f;
  for (int cc=0; cc<4; cc++){
    int c0 = kq*512 + cc*128;
    __syncthreads();
    hrow[kq][o] = x[c0 + o];
    __syncthreads();
    const float* W = P.W_out + (size_t)c0*OUTD + o;
    for (int j=0;j<128;j++) acc += hrow[kq][j]*W[(size_t)j*OUTD];
  }
  part[kq][o] = acc;
  __syncthreads();
  if (kq==0){
    float ns = f[OSS1+n]/(f[ODEG1+n]+1e-6f);
    float a = part[0][o]+part[1][o]+part[2][o]+part[3][o];
    float v = a*ns;
    f[OWH2 + (size_t)n*OUTD + o] = v;
    sr[o] = v*P.ao_src[o];
    dr[o] = v*P.ao_dst[o];
  }
  __syncthreads();
  for (int s=64;s>0;s>>=1){
    if (tid<s){ sr[tid]+=sr[tid+s]; dr[tid]+=dr[tid+s]; }
    __syncthreads();
  }
  if (tid==0){ f[OAS2+n]=sr[0]; f[OAD2+n]=dr[0]; }
}

// ---- GAT layer 2; fused xs2/xd2 + g3 raw gate dot ----
__global__ void k_att2(Params P){
  int n = blockIdx.x, g = blockIdx.y, tid = threadIdx.x;
  __shared__ float z[N];
  __shared__ float red[128];
  __shared__ float dred[128];
  __shared__ float gred[128];
  float* f = gf(g);
  const float* adj = P.g[g].adj;
  const int* pidx = gpidx(g);
  float asn = f[OAS2+n];
  const float* adn = f + OAD2;
  for (int j = tid; j < N; j += 128){
    float a = adj[n*N + j];
    float zz;
    if (a > 0.f){
      int p = pidx[n*N + j];
      float ee = (p >= 0) ? f[OEWV+p]*f[OS1+p] : 0.f;
      zz = lreluf(asn + adn[j] + ee);
    } else zz = -1e9f;
    z[j] = zz;
  }
  __syncthreads();
  float m = -3e38f;
  for (int j = tid; j < N; j += 128) m = fmaxf(m, z[j]);
  red[tid] = m; __syncthreads();
  for (int s=64;s>0;s>>=1){ if (tid<s) red[tid]=fmaxf(red[tid],red[tid+s]); __syncthreads(); }
  m = red[0]; __syncthreads();
  float ssum = 0.f;
  for (int j = tid; j < N; j += 128){ float e = expf(z[j]-m); z[j]=e; ssum += e; }
  red[tid] = ssum; __syncthreads();
  for (int s=64;s>0;s>>=1){ if (tid<s) red[tid]+=red[tid+s]; __syncthreads(); }
  float inv = 1.f/red[0]; __syncthreads();
  const float* wh = f + OWH2;
  float acc = 0.f;
  for (int j=0;j<N;j++){
    float w = z[j];
    if (w != 0.f) acc += w * wh[(size_t)j*OUTD + tid];
  }
  float v = acc*inv;
  f[OH2B + (size_t)n*OUTD + tid] = v;
  red[tid]  = v*P.ep2_w[tid];
  dred[tid] = v*P.ep2_w[OUTD+tid];
  gred[tid] = v*P.g3_w[tid];
  __syncthreads();
  for (int s=64;s>0;s>>=1){
    if (tid<s){ red[tid]+=red[tid+s]; dred[tid]+=dred[tid+s]; gred[tid]+=gred[tid+s]; }
    __syncthreads();
  }
  if (tid==0){ f[OXS2+n]=red[0]; f[OXD2+n]=dred[0]; f[ORAW3+n]=gred[0]; }
}

// ---- e2 path via bf16 MFMA v3: 32 edges x 2 heads per block (hg=8), K=256 mm2.
// Explicit register prefetch of all Wg (mm1) and Wo (mm2) fragments; EDOTH fused
// (pre-elu d . a_e). 1600 blocks for latency hiding.
__global__ __launch_bounds__(256) void k_e2p_mfma(Params P){
  int eb = blockIdx.x, hg = blockIdx.y, g = blockIdx.z;
  int tid = threadIdx.x;
  int wave = tid>>6, lane = tid&63, l16 = lane&15, l4 = lane>>4;
  __shared__ __attribute__((aligned(16))) u16 Tlds[32*256];   // 16KB, row-XOR swizzled
  int e0 = eb*32;
  int nt0 = wave*2;
  const u16* ea = G_EATTR_BF + ((size_t)g*E + e0)*HID;
  short8_t af00 = *(const short8_t*)(ea + l16*HID + l4*8);
  short8_t af01 = *(const short8_t*)(ea + l16*HID + 32 + l4*8);
  short8_t af10 = *(const short8_t*)(ea + (16+l16)*HID + l4*8);
  short8_t af11 = *(const short8_t*)(ea + (16+l16)*HID + 32 + l4*8);
  // ---- prefetch ALL mm1 weight fragments (static-indexed, fully unrolled) ----
  short8_t wg[2][2][2];   // [hh][nn][kk]
  #pragma unroll
  for (int hh=0; hh<2; hh++){
    const u16* Wg = G_WGAT_T + (size_t)(hg*2+hh)*OUTD*HID;
    #pragma unroll
    for (int nn=0; nn<2; nn++){
      const u16* Wgn = Wg + (size_t)((nt0+nn)*16 + l16)*HID + l4*8;
      wg[hh][nn][0] = *(const short8_t*)Wgn;
      wg[hh][nn][1] = *(const short8_t*)(Wgn + 32);
    }
  }
  float ew1p[2][4], ewvp[2][4], edp[2][2][4];
  #pragma unroll
  for (int t=0;t<2;t++)
    #pragma unroll
    for (int r=0;r<4;r++){ ew1p[t][r]=0.f; ewvp[t][r]=0.f; edp[0][t][r]=0.f; edp[1][t][r]=0.f; }
  // ---- mm1 compute: 2 heads x 2 col-tiles x 2 edge-tiles ----
  #pragma unroll
  for (int hh=0; hh<2; hh++){
    int h = hg*2 + hh;
    #pragma unroll
    for (int nn=0; nn<2; nn++){
      int nt = nt0 + nn;
      f32x4 d0 = {0.f,0.f,0.f,0.f}, d1 = {0.f,0.f,0.f,0.f};
      d0 = bmfma(af00, wg[hh][nn][0], d0);
      d1 = bmfma(af10, wg[hh][nn][0], d1);
      d0 = bmfma(af01, wg[hh][nn][1], d0);
      d1 = bmfma(af11, wg[hh][nn][1], d1);
      int qg = h*OUTD + nt*16 + l16;
      float ae = P.a_e[qg];
      float w1 = P.ep1_w[2*CAT + qg];
      float wv = gv_e()[qg];
      int qloc = hh*128 + nt*16 + l16;
      #pragma unroll
      for (int r=0;r<4;r++){
        edp[hh][0][r] += d0[r]*ae;
        edp[hh][1][r] += d1[r]*ae;
        float v0 = d0[r] > 0.f ? d0[r] : expm1f(d0[r]);
        float v1 = d1[r] > 0.f ? d1[r] : expm1f(d1[r]);
        ew1p[0][r] += v0*w1; ewvp[0][r] += v0*wv;
        ew1p[1][r] += v1*w1; ewvp[1][r] += v1*wv;
        int row = l4*4 + r;
        int byt = (row*512 + qloc*2) ^ ((row&7)<<4);
        *(u16*)((char*)Tlds + byt) = bf16rne(v0);
        *(u16*)((char*)Tlds + byt + 8192) = bf16rne(v1);   // rows 16..31
      }
    }
  }
  // ---- prefetch ALL mm2 Wo fragments (latency hides under reductions+barrier) ----
  const u16* WoA = G_WOUT_T + (size_t)(wave*32 + l16)*CAT + hg*256 + l4*8;
  const u16* WoB = WoA + 16*CAT;
  short8_t woa[8], wob[8];
  #pragma unroll
  for (int ks=0; ks<8; ks++){
    woa[ks] = *(const short8_t*)(WoA + ks*32);
    wob[ks] = *(const short8_t*)(WoB + ks*32);
  }
  // ---- reductions + atomics (fire-and-forget, before barrier) ----
  float* f = gf(g);
  #pragma unroll
  for (int r=0;r<4;r++){
    float a0 = ew1p[0][r], b0 = ewvp[0][r], a1 = ew1p[1][r], b1 = ewvp[1][r];
    a0 += __shfl_xor(a0,1); b0 += __shfl_xor(b0,1); a1 += __shfl_xor(a1,1); b1 += __shfl_xor(b1,1);
    a0 += __shfl_xor(a0,2); b0 += __shfl_xor(b0,2); a1 += __shfl_xor(a1,2); b1 += __shfl_xor(b1,2);
    a0 += __shfl_xor(a0,4); b0 += __shfl_xor(b0,4); a1 += __shfl_xor(a1,4); b1 += __shfl_xor(b1,4);
    a0 += __shfl_xor(a0,8); b0 += __shfl_xor(b0,8); a1 += __shfl_xor(a1,8); b1 += __shfl_xor(b1,8);
    if (l16==0){
      int e = e0 + l4*4 + r;
      atomicAdd(&f[OEW1+e], a0);
      atomicAdd(&f[OEWV+e], b0);
      atomicAdd(&f[OEW1+e+16], a1);
      atomicAdd(&f[OEWV+e+16], b1);
    }
  }
  #pragma unroll
  for (int hh=0; hh<2; hh++){
    float* eo = G_EDOTH + ((size_t)g*NH + hg*2 + hh)*E + e0;
    #pragma unroll
    for (int r=0;r<4;r++){
      float c0 = edp[hh][0][r], c1 = edp[hh][1][r];
      c0 += __shfl_xor(c0,1); c1 += __shfl_xor(c1,1);
      c0 += __shfl_xor(c0,2); c1 += __shfl_xor(c1,2);
      c0 += __shfl_xor(c0,4); c1 += __shfl_xor(c1,4);
      c0 += __shfl_xor(c0,8); c1 += __shfl_xor(c1,8);
      if (l16==0){
        atomicAdd(&eo[l4*4 + r], c0);
        atomicAdd(&eo[16 + l4*4 + r], c1);
      }
    }
  }
  __syncthreads();
  // ---- mm2: 8 K-steps, all Wo already in registers, 4 independent acc chains ----
  f32x4 acc00 = {0.f,0.f,0.f,0.f}, acc01 = {0.f,0.f,0.f,0.f};
  f32x4 acc10 = {0.f,0.f,0.f,0.f}, acc11 = {0.f,0.f,0.f,0.f};
  #pragma unroll
  for (int ks=0; ks<8; ks++){
    int byt = (l16*512 + ks*64 + l4*16) ^ ((l16&7)<<4);
    short8_t a0 = *(const short8_t*)((const char*)Tlds + byt);
    short8_t a1 = *(const short8_t*)((const char*)Tlds + byt + 8192);
    acc00 = bmfma(a0, woa[ks], acc00);
    acc10 = bmfma(a1, woa[ks], acc10);
    acc01 = bmfma(a0, wob[ks], acc01);
    acc11 = bmfma(a1, wob[ks], acc11);
  }
  // ---- store partials: [hg][g][e][128] ----
  float* dst = G_E2PART + (((size_t)hg*2 + g)*E + e0)*OUTD;
  #pragma unroll
  for (int r=0;r<4;r++){
    int ee = l4*4 + r;
    dst[(size_t)ee*OUTD + wave*32 + l16]      = acc00[r];
    dst[(size_t)ee*OUTD + wave*32 + 16 + l16] = acc01[r];
    dst[(size_t)(16+ee)*OUTD + wave*32 + l16]      = acc10[r];
    dst[(size_t)(16+ee)*OUTD + wave*32 + 16 + l16] = acc11[r];
  }
}

// ---- finish: sum 8 head-group partials, elu, dot ep2_w; fused s2 ----
constexpr int TE2 = 16;
__global__ void k_ew2fin(Params P){
  int e0 = blockIdx.x*TE2, g = blockIdx.y, tid = threadIdx.x;
  __shared__ float lred[2][TE2];
  float* f = gf(g);
  float w2 = P.ep2_w[2*OUTD + tid];
  int lane = tid & 63, wvi = tid >> 6;
  for (int e=0;e<TE2;e++){
    const float* src = G_E2PART + ((size_t)g*E + e0 + e)*OUTD + tid;
    float a = 0.f;
    #pragma unroll
    for (int h=0;h<8;h++) a += src[(size_t)h*2*E*OUTD];
    float v = eluf(f[OS1+e0+e]*a) * w2;
    for (int off=32;off>0;off>>=1) v += __shfl_down(v,off);
    if (lane==0) lred[wvi][e]=v;
  }
  __syncthreads();
  if (tid < TE2){
    int e = e0 + tid;
    float ew2 = lred[0][tid]+lred[1][tid];
    const int* ei = P.g[g].eidx;
    int s = ei[e], d = ei[E+e];
    float v = sigmf(f[OXS2+s] + f[OXD2+d] + ew2 + P.ep2_b[0]);
    atomicAdd(&f[OSS2+s], v);
    atomicAdd(&f[ODEG2+s], 1.f);
  }
}

// ---- LSTM input projection ----
__global__ void k_lstm_xg(Params P, int layer){
  int gid = blockIdx.x*4 + (threadIdx.x>>6);
  int lane = threadIdx.x & 63;
  int t = gid >> 10;
  int rem = gid & 1023;
  int d = rem >> 9;
  int gate = rem & 511;
  const float* Wih = layer ? P.Wih1 : P.Wih0;
  const float* bb  = layer ? P.b1   : P.b0;
  const float* xin = layer ? gy0()  : gxseq();
  int Din = layer ? 256 : SEQD;
  const float* x = xin + t*Din;
  const float* Wr = Wih + ((size_t)d*512 + gate)*Din;
  float acc = 0.f;
  for (int k=lane; k<Din; k+=64) acc += x[k]*Wr[k];
  for (int off=32; off>0; off>>=1) acc += __shfl_down(acc, off);
  if (lane==0) gxg()[(t*2 + d)*512 + gate] = acc + bb[d*512 + gate];
}

// ---- LSTM recurrence: coalesced via transposed Whh ----
__global__ void k_lstm_rec(Params P, int layer){
  int d = blockIdx.x, tid = threadIdx.x;
  float* yout = layer ? gy1() : gy0();
  const float* T = G_WHHT + (size_t)(layer*2 + d)*128*512;
  __shared__ float h[128], c[128], gbuf[512];
  if (tid < 128){ h[tid]=0.f; c[tid]=0.f; }
  __syncthreads();
  for (int s=0;s<2;s++){
    int t = (d==0) ? s : 1-s;
    float acc = gxg()[(t*2 + d)*512 + tid];
    for (int k=0;k<128;k++) acc += h[k]*T[(size_t)k*512 + tid];
    gbuf[tid] = acc;
    __syncthreads();
    if (tid < 128){
      float ii = sigmf(gbuf[tid]);
      float ff = sigmf(gbuf[128+tid]);
      float gg = tanhf(gbuf[256+tid]);
      float oo = sigmf(gbuf[384+tid]);
      float cn = ff*c[tid] + ii*gg;
      c[tid] = cn;
      float hn = oo*tanhf(cn);
      h[tid] = hn;
      yout[t*256 + d*128 + tid] = hn;
    }
    __syncthreads();
  }
}

// ---------------- final FC + softmax ----------------
__global__ void k_final(Params P){
  int tid = threadIdx.x;
  __shared__ float sb[256], sb2[256];
  const float* x = gy1() + 256;
  sb[tid]  = x[tid]*P.fc_w[tid*2+0];
  sb2[tid] = x[tid]*P.fc_w[tid*2+1];
  __syncthreads();
  for (int s=128;s>0;s>>=1){ if (tid<s){ sb[tid]+=sb[tid+s]; sb2[tid]+=sb2[tid+s]; } __syncthreads(); }
  if (tid==0){
    float l0 = sb[0] + P.fc_b[0];
    float l1 = sb2[0] + P.fc_b[1];
    float m = fmaxf(l0,l1);
    float e0 = expf(l0-m), e1 = expf(l1-m), inv = 1.f/(e0+e1);
    P.out[0] = e0*inv;
    P.out[1] = e1*inv;
  }
}

extern "C" void kernel_launch(void* const* d_in, const int* in_sizes, int n_in,
                              void* d_out, int out_size, void* d_ws, size_t ws_size,
                              hipStream_t stream){
  Params P;
  for (int g=0; g<2; ++g){
    int b = g*5;
    P.g[g].feat  = (const float*)d_in[b+0];
    P.g[g].eidx  = (const int*)d_in[b+1];
    P.g[g].eattr = (const float*)d_in[b+2];
    P.g[g].adj   = (const float*)d_in[b+3];
    P.g[g].n2n   = (const float*)d_in[b+4];
  }
  P.W_h   = (const float*)d_in[10];
  P.W_gat = (const float*)d_in[11];
  P.a_src = (const float*)d_in[12];
  P.a_dst = (const float*)d_in[13];
  P.a_e   = (const float*)d_in[14];
  P.We_gat= (const float*)d_in[15];
  P.W_out = (const float*)d_in[16];
  P.ao_src= (const float*)d_in[17];
  P.ao_dst= (const float*)d_in[18];
  P.ao_e  = (const float*)d_in[19];
  P.We_out= (const float*)d_in[20];
  P.ep1_w = (const float*)d_in[21];
  P.ep1_b = (const float*)d_in[22];
  P.ep2_w = (const float*)d_in[23];
  P.ep2_b = (const float*)d_in[24];
  P.g1_w  = (const float*)d_in[25];
  P.g1_b  = (const float*)d_in[26];
  P.g2_w  = (const float*)d_in[27];
  P.g2_b  = (const float*)d_in[28];
  P.g3_w  = (const float*)d_in[29];
  P.g3_b  = (const float*)d_in[30];
  P.Wih0  = (const float*)d_in[31];
  P.Whh0  = (const float*)d_in[32];
  P.b0    = (const float*)d_in[33];
  P.Wih1  = (const float*)d_in[34];
  P.Whh1  = (const float*)d_in[35];
  P.b1    = (const float*)d_in[36];
  P.fc_w  = (const float*)d_in[37];
  P.fc_b  = (const float*)d_in[38];
  P.out   = (float*)d_out;

  // ---- graph stages ----
  k_init <<<dim3(IB_Z+IB_C+IB_D+IB_E+IB_H+IB_W1+IB_W2+IB_EA), 256, 0, stream>>>(P);
  k_pairs<<<dim3((E+255)/256,2), 256, 0, stream>>>(P);
  k_e2p_mfma<<<dim3(E/32, 8, 2), 256, 0, stream>>>(P);
  k_Wh   <<<dim3(N,NH+1,2), 128, 0, stream>>>(P);      // +gpool1 slice
  k_att1 <<<dim3(N/4,NH,2),128, 0, stream>>>(P);
  k_xw1  <<<dim3(N,2),    256, 0, stream>>>(P);
  k_s1   <<<dim3((E+255)/256,2), 256, 0, stream>>>(P);
  k_gpool_out<<<dim3(8,2), 256, 0, stream>>>(P, OH1, CAT, ODEG1, ORAW2, P.g2_b, HID);
  k_Wh2  <<<dim3(N,2),    512, 0, stream>>>(P);
  k_att2 <<<dim3(N,2),    128, 0, stream>>>(P);
  k_ew2fin<<<dim3(E/TE2,2),128, 0, stream>>>(P);       // +s2
  k_gpool_out<<<dim3(1,2), 256, 0, stream>>>(P, OH2B, OUTD, ODEG2, ORAW3, P.g3_b, HID+CAT);

  // ---- LSTM stack + classifier ----
  k_lstm_xg <<<dim3(512), 256, 0, stream>>>(P, 0);
  k_lstm_rec<<<dim3(2),   512, 0, stream>>>(P, 0);
  k_lstm_xg <<<dim3(512), 256, 0, stream>>>(P, 1);
  k_lstm_rec<<<dim3(2),   512, 0, stream>>>(P, 1);
  k_final<<<dim3(1), 256, 0, stream>>>(P);
}

// Round 4
// 338.284 us; speedup vs baseline: 1.1197x; 1.1197x over previous
//
#include <hip/hip_runtime.h>
#include <math.h>

#define DI static __device__ __forceinline__

DI float eluf(float x){ return x > 0.f ? x : expm1f(x); }
DI float lreluf(float x){ return x > 0.f ? x : 0.2f*x; }
DI float sigmf(float x){ return 1.f/(1.f+expf(-x)); }

typedef unsigned short u16;
typedef unsigned int   u32;
typedef __attribute__((ext_vector_type(8))) short short8_t;
typedef __attribute__((ext_vector_type(4))) float f32x4;

DI u16 bf16rne(float f){
  u32 u = __float_as_uint(f);
  u += 0x7fffu + ((u>>16)&1u);
  return (u16)(u>>16);
}

DI f32x4 bmfma(short8_t a, short8_t b, f32x4 c){
  return __builtin_amdgcn_mfma_f32_16x16x32_bf16(a, b, c, 0, 0, 0);
}

constexpr int N=200, E=3200, HID=64, NH=16, OUTD=128, CAT=2048, SEQD=2240;

// ---- per-graph f32 scratch offsets (in floats) ----
constexpr int OH0   = 0;
constexpr int OWH   = OH0 + N*HID;
constexpr int OASN  = OWH + NH*N*OUTD;
constexpr int OADN  = OASN + NH*N;
constexpr int OH1   = OADN + NH*N;
constexpr int OXW1  = OH1 + N*CAT;
constexpr int OXW2  = OXW1 + 256;
constexpr int OEW1  = OXW2 + 256;
constexpr int OS1   = OEW1 + E;
constexpr int ODEG1 = OS1 + E;
constexpr int OSS1  = ODEG1 + 256;   // = ODEG1+256 (inline ns relies on this)
constexpr int ORAW1 = OSS1 + 256;
constexpr int OWH2  = ORAW1 + 256;
constexpr int OAS2  = OWH2 + N*OUTD;
constexpr int OAD2  = OAS2 + 256;
constexpr int OEWV  = OAD2 + 256;
constexpr int OH2B  = OEWV + E;
constexpr int OXS2  = OH2B + N*OUTD;
constexpr int OXD2  = OXS2 + 256;
constexpr int ODEG2 = OXD2 + 256;
constexpr int OSS2  = ODEG2 + 256;   // = ODEG2+256
constexpr int ORAW2 = OSS2 + 256;
constexpr int ORAW3 = ORAW2 + 256;
constexpr int PGF   = ORAW3 + 256;
constexpr int GLOBF = 10624;
constexpr int TOTF  = GLOBF + 2*PGF;

// ---- static device scratch ----
__device__ __attribute__((aligned(16))) float G_F[TOTF];
__device__ float G_E2PART[(size_t)4*2*E*OUTD];    // ew2full partials [hg=4][g][e][128]
__device__ float G_EDOTH[2*NH*E];
__device__ float G_WHHT[2*2*128*512];
__device__ int   G_PIDX[2*N*N];
__device__ __attribute__((aligned(16))) u16 G_WGAT_T[NH*OUTD*HID];  // [h][o][c] bf16
__device__ __attribute__((aligned(16))) u16 G_WOUT_T[OUTD*CAT];     // [n][q] bf16
__device__ __attribute__((aligned(16))) u16 G_EATTR_BF[2*E*HID];    // [g][e][c] bf16

DI float* gf(int g){ return G_F + GLOBF + (size_t)g*PGF; }
DI float* gwe_ae(){ return G_F; }
DI float* gv_e(){ return G_F + 1024; }
DI float* gy0(){ return G_F + 3072; }
DI float* gy1(){ return G_F + 3584; }
DI float* gxseq(){ return G_F + 4096; }
DI float* gxg(){ return G_F + 8576; }
DI int*   gpidx(int g){ return G_PIDX + g*N*N; }

struct GraphIn {
  const float *feat, *eattr, *adj, *n2n;
  const int   *eidx;
};

struct Params {
  GraphIn g[2];
  const float *W_h, *W_gat, *a_src, *a_dst, *a_e, *We_gat;
  const float *W_out, *ao_src, *ao_dst, *ao_e, *We_out;
  const float *ep1_w, *ep1_b, *ep2_w, *ep2_b;
  const float *g1_w, *g1_b, *g2_w, *g2_b, *g3_w, *g3_b;
  const float *Wih0, *Whh0, *b0, *Wih1, *Whh1, *b1, *fc_w, *fc_b;
  float *out;
};

// ---- fused init: zero atomics, pidx=-1, Whh^T, precontract, h0+g1dot, bf16 converts ----
constexpr int ZPG  = 2*E + 1024;              // per-graph floats to zero
constexpr int IB_Z = (2*ZPG+255)/256;
constexpr int IB_C = (2*N*N+255)/256;
constexpr int IB_D = (2*2*512*128)/256;
constexpr int IB_E = (NH*HID+CAT+3)/4;
constexpr int IB_H = (2*N+3)/4;
constexpr int IB_W1 = (NH*OUTD*HID)/256;      // 512
constexpr int IB_W2 = (OUTD*CAT)/256;         // 1024
constexpr int IB_EA = (2*E*HID)/256;          // 1600
__global__ void k_init(Params P){
  int b = blockIdx.x, tid = threadIdx.x;
  if (b < IB_Z){
    int i = b*256 + tid;
    if (i < 2*ZPG){
      int g = i/ZPG, r = i%ZPG;
      int addr = r<E ? OEW1+r : (r<2*E ? OEWV+(r-E) :
                 (r<2*E+512 ? ODEG1+(r-2*E) : ODEG2+(r-2*E-512)));
      gf(g)[addr] = 0.f;
    }
  } else if (b < IB_Z+IB_C){
    int i = (b-IB_Z)*256 + tid; if (i < 2*N*N) G_PIDX[i] = -1;
  } else if (b < IB_Z+IB_C+IB_D){
    int idx = (b-IB_Z-IB_C)*256 + tid;
    int l = idx >> 17;
    int r = idx & 131071;
    int d = r >> 16;
    int r2 = r & 65535;
    int gate = r2 & 511;
    int k = r2 >> 9;
    const float* Whh = l ? P.Whh1 : P.Whh0;
    G_WHHT[idx] = Whh[((size_t)d*512+gate)*128 + k];
  } else if (b < IB_Z+IB_C+IB_D+IB_E){
    int gid = (b-IB_Z-IB_C-IB_D)*4 + (tid>>6);
    int lane = tid & 63;
    if (gid < NH*HID){
      int h = gid/HID, c = gid%HID;
      const float* W = P.We_gat + (size_t)(h*HID+c)*OUTD;
      const float* a = P.a_e + h*OUTD;
      float acc = 0.f;
      for (int o=lane;o<OUTD;o+=64) acc += W[o]*a[o];
      for (int off=32;off>0;off>>=1) acc += __shfl_down(acc,off);
      if (lane==0) gwe_ae()[gid] = acc;
    } else if (gid < NH*HID+CAT){
      int c = gid - NH*HID;
      const float* W = P.We_out + (size_t)c*OUTD;
      float acc = 0.f;
      for (int o=lane;o<OUTD;o+=64) acc += W[o]*P.ao_e[o];
      for (int off=32;off>0;off>>=1) acc += __shfl_down(acc,off);
      if (lane==0) gv_e()[c] = acc;
    }
  } else if (b < IB_Z+IB_C+IB_D+IB_E+IB_H){
    int unit = (b-IB_Z-IB_C-IB_D-IB_E)*4 + (tid>>6);
    if (unit >= 2*N) return;
    int g = unit / N, n = unit % N, c = tid & 63;
    const float* feat = P.g[g].feat;
    float acc = 0.f;
    for (int k=0;k<HID;k++) acc += feat[n*HID+k]*P.W_h[k*HID+c];
    float v = eluf(acc);
    float* f = gf(g);
    f[OH0 + n*HID + c] = v;
    float r = v*P.g1_w[c];
    for (int off=32;off>0;off>>=1) r += __shfl_down(r,off);
    if (c==0) f[ORAW1+n] = r;
  } else if (b < IB_Z+IB_C+IB_D+IB_E+IB_H+IB_W1){
    // We_gat [h][c][o] -> bf16 transposed [h][o][c]
    int i = (b-(IB_Z+IB_C+IB_D+IB_E+IB_H))*256 + tid;
    int h = i>>13, o = (i>>6)&127, c = i&63;
    G_WGAT_T[i] = bf16rne(P.We_gat[(size_t)(h*HID+c)*OUTD + o]);
  } else if (b < IB_Z+IB_C+IB_D+IB_E+IB_H+IB_W1+IB_W2){
    // We_out [q][n] -> bf16 transposed [n][q]
    int i = (b-(IB_Z+IB_C+IB_D+IB_E+IB_H+IB_W1))*256 + tid;
    int n = i>>11, q = i&2047;
    G_WOUT_T[i] = bf16rne(P.We_out[(size_t)q*OUTD + n]);
  } else {
    // eattr -> bf16 [g][e][c]
    int i = (b-(IB_Z+IB_C+IB_D+IB_E+IB_H+IB_W1+IB_W2))*256 + tid;
    int g = i >= E*HID ? 1 : 0;
    G_EATTR_BF[i] = bf16rne(P.g[g].eattr[i - g*E*HID]);
  }
}
constexpr int IB_TOT = IB_Z+IB_C+IB_D+IB_E+IB_H+IB_W1+IB_W2+IB_EA;

// ================= mega kernel bodies (independent stages, one launch) =========

// ---- e2p: 32 edges x 4 heads per block, K=512 mm2, rolling 2-deep Wo pipe ----
DI void e2p_body(Params& P, int idx, char* smem){
  int g = idx/400, r2 = idx%400, hg = r2/100, eb = r2%100;
  int tid = threadIdx.x;
  int wave = tid>>6, lane = tid&63, l16 = lane&15, l4 = lane>>4;
  u16* Tlds = (u16*)smem;                       // 32KB, row-XOR swizzled
  int e0 = eb*32;
  int nt0 = wave*2;
  const u16* ea = G_EATTR_BF + ((size_t)g*E + e0)*HID;
  short8_t af00 = *(const short8_t*)(ea + l16*HID + l4*8);
  short8_t af01 = *(const short8_t*)(ea + l16*HID + 32 + l4*8);
  short8_t af10 = *(const short8_t*)(ea + (16+l16)*HID + l4*8);
  short8_t af11 = *(const short8_t*)(ea + (16+l16)*HID + 32 + l4*8);
  float ew1p0[4] = {0.f,0.f,0.f,0.f}, ewvp0[4] = {0.f,0.f,0.f,0.f};
  float ew1p1[4] = {0.f,0.f,0.f,0.f}, ewvp1[4] = {0.f,0.f,0.f,0.f};
  // ---- mm1: 4 heads x 2 col-tiles, 2 independent edge-tile chains ----
  for (int hh=0; hh<4; hh++){
    int h = hg*4 + hh;
    const u16* Wg = G_WGAT_T + (size_t)h*OUTD*HID;
    #pragma unroll
    for (int nn=0; nn<2; nn++){
      int nt = nt0 + nn;
      const u16* Wgn = Wg + (size_t)(nt*16 + l16)*HID + l4*8;
      short8_t wg0 = *(const short8_t*)Wgn;
      short8_t wg1 = *(const short8_t*)(Wgn + 32);
      f32x4 d0 = {0.f,0.f,0.f,0.f}, d1 = {0.f,0.f,0.f,0.f};
      d0 = bmfma(af00, wg0, d0);
      d1 = bmfma(af10, wg0, d1);
      d0 = bmfma(af01, wg1, d0);
      d1 = bmfma(af11, wg1, d1);
      int qg = h*OUTD + nt*16 + l16;
      float w1 = P.ep1_w[2*CAT + qg];
      float wv = gv_e()[qg];
      int qloc = hh*128 + nt*16 + l16;
      #pragma unroll
      for (int r=0;r<4;r++){
        float v0 = d0[r] > 0.f ? d0[r] : expm1f(d0[r]);
        float v1 = d1[r] > 0.f ? d1[r] : expm1f(d1[r]);
        ew1p0[r] += v0*w1; ewvp0[r] += v0*wv;
        ew1p1[r] += v1*w1; ewvp1[r] += v1*wv;
        int row = l4*4 + r;
        int byt = (row*1024 + qloc*2) ^ ((row&7)<<4);
        *(u16*)((char*)Tlds + byt) = bf16rne(v0);
        *(u16*)((char*)Tlds + byt + 16384) = bf16rne(v1);   // rows 16..31
      }
    }
  }
  // ---- mm2 prologue Wo loads (independent of LDS): issue before barrier ----
  const u16* WoA = G_WOUT_T + (size_t)(wave*32 + l16)*CAT + hg*512 + l4*8;
  const u16* WoB = WoA + 16*CAT;
  short8_t w0a = *(const short8_t*)WoA;
  short8_t w0b = *(const short8_t*)WoB;
  short8_t w1a = *(const short8_t*)(WoA + 32);
  short8_t w1b = *(const short8_t*)(WoB + 32);
  // ---- ew1/ewv reduce + atomics (fire-and-forget, before barrier) ----
  float* f = gf(g);
  #pragma unroll
  for (int r=0;r<4;r++){
    float a0 = ew1p0[r], b0 = ewvp0[r], a1 = ew1p1[r], b1 = ewvp1[r];
    a0 += __shfl_xor(a0,1); b0 += __shfl_xor(b0,1); a1 += __shfl_xor(a1,1); b1 += __shfl_xor(b1,1);
    a0 += __shfl_xor(a0,2); b0 += __shfl_xor(b0,2); a1 += __shfl_xor(a1,2); b1 += __shfl_xor(b1,2);
    a0 += __shfl_xor(a0,4); b0 += __shfl_xor(b0,4); a1 += __shfl_xor(a1,4); b1 += __shfl_xor(b1,4);
    a0 += __shfl_xor(a0,8); b0 += __shfl_xor(b0,8); a1 += __shfl_xor(a1,8); b1 += __shfl_xor(b1,8);
    if (l16==0){
      int e = e0 + l4*4 + r;
      atomicAdd(&f[OEW1+e], a0);
      atomicAdd(&f[OEWV+e], b0);
      atomicAdd(&f[OEW1+e+16], a1);
      atomicAdd(&f[OEWV+e+16], b1);
    }
  }
  __syncthreads();
  // ---- mm2: 16 K-steps, 2-deep register pipeline, 4 acc chains ----
  f32x4 acc00 = {0.f,0.f,0.f,0.f}, acc01 = {0.f,0.f,0.f,0.f};
  f32x4 acc10 = {0.f,0.f,0.f,0.f}, acc11 = {0.f,0.f,0.f,0.f};
  #pragma unroll
  for (int ks=0; ks<16; ks++){
    short8_t na = w0a, nb = w0b;
    if (ks < 14){
      na = *(const short8_t*)(WoA + (ks+2)*32);
      nb = *(const short8_t*)(WoB + (ks+2)*32);
    }
    int byt = (l16*1024 + ks*64 + l4*16) ^ ((l16&7)<<4);
    short8_t a0 = *(const short8_t*)((const char*)Tlds + byt);
    short8_t a1 = *(const short8_t*)((const char*)Tlds + byt + 16384);
    acc00 = bmfma(a0, w0a, acc00);
    acc10 = bmfma(a1, w0a, acc10);
    acc01 = bmfma(a0, w0b, acc01);
    acc11 = bmfma(a1, w0b, acc11);
    w0a = w1a; w0b = w1b; w1a = na; w1b = nb;
  }
  // ---- store partials: [hg][g][e][128] ----
  float* dst = G_E2PART + (((size_t)hg*2 + g)*E + e0)*OUTD;
  #pragma unroll
  for (int r=0;r<4;r++){
    int ee = l4*4 + r;
    dst[(size_t)ee*OUTD + wave*32 + l16]      = acc00[r];
    dst[(size_t)ee*OUTD + wave*32 + 16 + l16] = acc01[r];
    dst[(size_t)(16+ee)*OUTD + wave*32 + l16]      = acc10[r];
    dst[(size_t)(16+ee)*OUTD + wave*32 + 16 + l16] = acc11[r];
  }
}

// ---- EDOTH fp32: 16 edges x 16 heads per block, LDS-staged (+1 pad) ----
DI void edoth_body(Params& P, int idx, float* s){
  int tid = threadIdx.x;
  int g = idx / (E/16);
  int e0 = (idx % (E/16)) * 16;
  float (*ea)[HID+1] = (float(*)[HID+1])s;
  float (*wa)[HID+1] = (float(*)[HID+1])(s + 16*(HID+1));
  {
    int row = tid >> 4, c0 = (tid & 15)*4;
    float4 v = *(const float4*)&P.g[g].eattr[(size_t)(e0+row)*HID + c0];
    ea[row][c0]=v.x; ea[row][c0+1]=v.y; ea[row][c0+2]=v.z; ea[row][c0+3]=v.w;
    float4 w = *(const float4*)&gwe_ae()[row*HID + c0];
    wa[row][c0]=w.x; wa[row][c0+1]=w.y; wa[row][c0+2]=w.z; wa[row][c0+3]=w.w;
  }
  __syncthreads();
  int h = tid >> 4, el = tid & 15;
  float acc = 0.f;
  #pragma unroll
  for (int c=0;c<HID;c++) acc += ea[el][c]*wa[h][c];
  G_EDOTH[((size_t)g*NH + h)*E + e0 + el] = acc;
}

// ---- Wh: one (n,h) per block (tid<128 active); h==NH slice does gpool1 ----
DI void wh_body(Params& P, int idx, float* s){
  int o = threadIdx.x;
  if (o >= 128) return;     // full waves 2-3 exit before any barrier
  int g = idx / (N*(NH+1));
  int r = idx % (N*(NH+1));
  int h = r / N, n = r % N;
  float* f = gf(g);
  if (h == NH){
    if (n != 0) return;
    float* att = s;          // [N]
    float* sb  = s + 200;    // [128]
    for (int j = o; j < N; j += 128) att[j] = sigmf(f[ORAW1+j] + P.g1_b[0]);
    __syncthreads();
    float m = -3e38f;
    for (int j = o; j < N; j += 128) m = fmaxf(m, att[j]);
    sb[o] = m; __syncthreads();
    for (int sft=64;sft>0;sft>>=1){ if (o<sft) sb[o]=fmaxf(sb[o],sb[o+sft]); __syncthreads(); }
    m = sb[0]; __syncthreads();
    float ss = 0.f;
    for (int j = o; j < N; j += 128){ float e = expf(att[j]-m); ss += e; }
    sb[o] = ss; __syncthreads();
    for (int sft=64;sft>0;sft>>=1){ if (o<sft) sb[o]+=sb[o+sft]; __syncthreads(); }
    float inv = 1.f/sb[0]; __syncthreads();
    for (int j = o; j < N; j += 128) att[j] = expf(att[j]-m)*inv;
    __syncthreads();
    if (o < HID){
      float acc = 0.f;
      for (int j=0;j<N;j++) acc += att[j]*f[OH0 + j*HID + o];
      gxseq()[g*SEQD + o] = acc;
    }
    return;
  }
  float* hs   = s;          // [64]
  float* sred = s + 64;     // [128]
  float* dred = s + 192;    // [128]
  if (o < HID) hs[o] = f[OH0 + n*HID + o];
  __syncthreads();
  const float* W = P.W_gat + (size_t)h*HID*OUTD + o;
  float acc = 0.f;
  for (int c=0;c<HID;c++) acc += hs[c]*W[(size_t)c*OUTD];
  f[OWH + ((size_t)h*N + n)*OUTD + o] = acc;
  sred[o] = acc*P.a_src[h*OUTD+o];
  dred[o] = acc*P.a_dst[h*OUTD+o];
  __syncthreads();
  for (int sft=64;sft>0;sft>>=1){ if (o<sft){ sred[o]+=sred[o+sft]; dred[o]+=dred[o+sft]; } __syncthreads(); }
  if (o==0){ f[OASN+h*N+n]=sred[0]; f[OADN+h*N+n]=dred[0]; }
}

// ---- pairIdx: last edge wins ----
DI void pairs_body(Params& P, int idx){
  int g = idx / 13;
  int e = (idx % 13)*256 + threadIdx.x;
  if (e >= E) return;
  const int* ei = P.g[g].eidx;
  atomicMax(&gpidx(g)[ei[e]*N + ei[E+e]], e);
}

constexpr int MB_E2P = 800, MB_ED = 400, MB_WH = 2*N*(NH+1), MB_PR = 26;
__global__ __launch_bounds__(256) void k_mega(Params P){
  __shared__ __attribute__((aligned(16))) char smem[32768];
  int b = blockIdx.x;
  if (b < MB_E2P) e2p_body(P, b, smem);
  else if (b < MB_E2P+MB_ED) edoth_body(P, b-MB_E2P, (float*)smem);
  else if (b < MB_E2P+MB_ED+MB_WH) wh_body(P, b-(MB_E2P+MB_ED), (float*)smem);
  else pairs_body(P, b-(MB_E2P+MB_ED+MB_WH));
}

// ---- GAT layer 1: 4 nodes/block ----
__global__ void k_att1(Params P){
  int nb = blockIdx.x, h = blockIdx.y, g = blockIdx.z, tid = threadIdx.x;
  int n0 = nb*4;
  __shared__ float z[4][N];
  __shared__ float red[128];
  __shared__ float sinv[4];
  float* f = gf(g);
  const float* adj = P.g[g].adj;
  const int* pidx = gpidx(g);
  const float* edoth = G_EDOTH + ((size_t)g*NH + h)*E;
  const float* adn = f + OADN + h*N;
  for (int i=0;i<4;i++){
    float asn = f[OASN + h*N + n0+i];
    for (int j = tid; j < N; j += 128){
      float a = adj[(n0+i)*N + j];
      float zz;
      if (a > 0.f){
        int p = pidx[(n0+i)*N + j];
        float ee = (p >= 0) ? edoth[p] : 0.f;
        zz = lreluf(asn + adn[j] + ee);
      } else zz = -1e9f;
      z[i][j] = zz;
    }
  }
  __syncthreads();
  for (int i=0;i<4;i++){
    float m = -3e38f;
    for (int j = tid; j < N; j += 128) m = fmaxf(m, z[i][j]);
    red[tid] = m; __syncthreads();
    for (int s=64;s>0;s>>=1){ if (tid<s) red[tid]=fmaxf(red[tid],red[tid+s]); __syncthreads(); }
    m = red[0]; __syncthreads();
    float ssum = 0.f;
    for (int j = tid; j < N; j += 128){ float e = expf(z[i][j]-m); z[i][j]=e; ssum += e; }
    red[tid] = ssum; __syncthreads();
    for (int s=64;s>0;s>>=1){ if (tid<s) red[tid]+=red[tid+s]; __syncthreads(); }
    if (tid==0) sinv[i] = 1.f/red[0];
    __syncthreads();
  }
  const float* wh = f + OWH + (size_t)h*N*OUTD;
  float a0=0.f,a1=0.f,a2=0.f,a3=0.f;
  for (int j=0;j<N;j++){
    float w = wh[(size_t)j*OUTD + tid];
    a0 += z[0][j]*w; a1 += z[1][j]*w; a2 += z[2][j]*w; a3 += z[3][j]*w;
  }
  f[OH1 + (size_t)(n0+0)*CAT + h*OUTD + tid] = eluf(a0*sinv[0]);
  f[OH1 + (size_t)(n0+1)*CAT + h*OUTD + tid] = eluf(a1*sinv[1]);
  f[OH1 + (size_t)(n0+2)*CAT + h*OUTD + tid] = eluf(a2*sinv[2]);
  f[OH1 + (size_t)(n0+3)*CAT + h*OUTD + tid] = eluf(a3*sinv[3]);
}

// ---- pool1 node dots + fused g2 raw gate dot ----
__global__ void k_xw1(Params P){
  int n = blockIdx.x, g = blockIdx.y, tid = threadIdx.x;
  __shared__ float s1b[256], s2b[256], s3b[256];
  float* f = gf(g);
  const float* x = f + OH1 + (size_t)n*CAT;
  float a1 = 0.f, a2 = 0.f, a3 = 0.f;
  for (int c = tid; c < CAT; c += 256){
    float xv = x[c];
    a1 += xv*P.ep1_w[c];
    a2 += xv*P.ep1_w[CAT+c];
    a3 += xv*P.g2_w[c];
  }
  s1b[tid]=a1; s2b[tid]=a2; s3b[tid]=a3; __syncthreads();
  for (int s=128;s>0;s>>=1){
    if (tid<s){ s1b[tid]+=s1b[tid+s]; s2b[tid]+=s2b[tid+s]; s3b[tid]+=s3b[tid+s]; }
    __syncthreads();
  }
  if (tid==0){ f[OXW1+n]=s1b[0]; f[OXW2+n]=s2b[0]; f[ORAW2+n]=s3b[0]; }
}

// ---------------- pool1 edge scores + segment sums ----------------
__global__ void k_s1(Params P){
  int e = blockIdx.x*256 + threadIdx.x, g = blockIdx.y;
  if (e >= E) return;
  float* f = gf(g);
  const int* ei = P.g[g].eidx;
  int s = ei[e], d = ei[E+e];
  float v = sigmf(f[OXW1+s] + f[OXW2+d] + f[OEW1+e] + P.ep1_b[0]);
  f[OS1+e] = v;
  atomicAdd(&f[OSS1+s], v);
  atomicAdd(&f[ODEG1+s], 1.f);
}

// ---- merged gpool 2+3: 512-thread generic body ----
DI void gpool_body(Params& P, int xoff, int D, int odeg, int rawoff,
                   const float* bb, int outoff, int cb, int g,
                   float* att, float* sb){
  int tid = threadIdx.x;
  float* f = gf(g);
  if (tid < N){
    float sc = f[odeg+256+tid]/(f[odeg+tid]+1e-6f);
    att[tid] = sigmf(f[rawoff+tid]*sc + bb[0]);
  }
  __syncthreads();
  float m = (tid < N) ? att[tid] : -3e38f;
  sb[tid] = m; __syncthreads();
  for (int s=256;s>0;s>>=1){ if (tid<s) sb[tid]=fmaxf(sb[tid],sb[tid+s]); __syncthreads(); }
  m = sb[0]; __syncthreads();
  float e = (tid < N) ? expf(att[tid]-m) : 0.f;
  sb[tid] = e; __syncthreads();
  for (int s=256;s>0;s>>=1){ if (tid<s) sb[tid]+=sb[tid+s]; __syncthreads(); }
  float inv = 1.f/sb[0]; __syncthreads();
  if (tid < N){
    float sc = f[odeg+256+tid]/(f[odeg+tid]+1e-6f);
    att[tid] = e*inv*sc;
  }
  __syncthreads();
  int c = cb*512 + tid;
  if (c < D){
    const float* x = f + xoff;
    float acc = 0.f;
    for (int n=0;n<N;n++) acc += att[n]*x[(size_t)n*D + c];
    gxseq()[g*SEQD + outoff + c] = acc;
  }
}

__global__ void k_gpools(Params P){
  __shared__ float att[N];
  __shared__ float sb[512];
  int b = blockIdx.x;
  if (b < 8){
    int g = b >> 2, cb = b & 3;
    gpool_body(P, OH1, CAT, ODEG1, ORAW2, P.g2_b, HID, cb, g, att, sb);
  } else {
    int g = b - 8;
    gpool_body(P, OH2B, OUTD, ODEG2, ORAW3, P.g3_b, HID+CAT, 0, g, att, sb);
  }
}

// ---- Wh2 (N,2; 512 thr) + fused asad2 tail ----
__global__ void k_Wh2(Params P){
  int n = blockIdx.x, g = blockIdx.y, tid = threadIdx.x;
  int kq = tid >> 7, o = tid & 127;
  __shared__ float hrow[4][128];
  __shared__ float part[4][128];
  __shared__ float sr[128], dr[128];
  float* f = gf(g);
  const float* x = f + OH1 + (size_t)n*CAT;
  float acc = 0.f;
  for (int cc=0; cc<4; cc++){
    int c0 = kq*512 + cc*128;
    __syncthreads();
    hrow[kq][o] = x[c0 + o];
    __syncthreads();
    const float* W = P.W_out + (size_t)c0*OUTD + o;
    for (int j=0;j<128;j++) acc += hrow[kq][j]*W[(size_t)j*OUTD];
  }
  part[kq][o] = acc;
  __syncthreads();
  if (kq==0){
    float ns = f[OSS1+n]/(f[ODEG1+n]+1e-6f);
    float a = part[0][o]+part[1][o]+part[2][o]+part[3][o];
    float v = a*ns;
    f[OWH2 + (size_t)n*OUTD + o] = v;
    sr[o] = v*P.ao_src[o];
    dr[o] = v*P.ao_dst[o];
  }
  __syncthreads();
  for (int s=64;s>0;s>>=1){
    if (tid<s){ sr[tid]+=sr[tid+s]; dr[tid]+=dr[tid+s]; }
    __syncthreads();
  }
  if (tid==0){ f[OAS2+n]=sr[0]; f[OAD2+n]=dr[0]; }
}

// ---- GAT layer 2; fused xs2/xd2 + g3 raw gate dot ----
__global__ void k_att2(Params P){
  int n = blockIdx.x, g = blockIdx.y, tid = threadIdx.x;
  __shared__ float z[N];
  __shared__ float red[128];
  __shared__ float dred[128];
  __shared__ float gred[128];
  float* f = gf(g);
  const float* adj = P.g[g].adj;
  const int* pidx = gpidx(g);
  float asn = f[OAS2+n];
  const float* adn = f + OAD2;
  for (int j = tid; j < N; j += 128){
    float a = adj[n*N + j];
    float zz;
    if (a > 0.f){
      int p = pidx[n*N + j];
      float ee = (p >= 0) ? f[OEWV+p]*f[OS1+p] : 0.f;
      zz = lreluf(asn + adn[j] + ee);
    } else zz = -1e9f;
    z[j] = zz;
  }
  __syncthreads();
  float m = -3e38f;
  for (int j = tid; j < N; j += 128) m = fmaxf(m, z[j]);
  red[tid] = m; __syncthreads();
  for (int s=64;s>0;s>>=1){ if (tid<s) red[tid]=fmaxf(red[tid],red[tid+s]); __syncthreads(); }
  m = red[0]; __syncthreads();
  float ssum = 0.f;
  for (int j = tid; j < N; j += 128){ float e = expf(z[j]-m); z[j]=e; ssum += e; }
  red[tid] = ssum; __syncthreads();
  for (int s=64;s>0;s>>=1){ if (tid<s) red[tid]+=red[tid+s]; __syncthreads(); }
  float inv = 1.f/red[0]; __syncthreads();
  const float* wh = f + OWH2;
  float acc = 0.f;
  for (int j=0;j<N;j++){
    float w = z[j];
    if (w != 0.f) acc += w * wh[(size_t)j*OUTD + tid];
  }
  float v = acc*inv;
  f[OH2B + (size_t)n*OUTD + tid] = v;
  red[tid]  = v*P.ep2_w[tid];
  dred[tid] = v*P.ep2_w[OUTD+tid];
  gred[tid] = v*P.g3_w[tid];
  __syncthreads();
  for (int s=64;s>0;s>>=1){
    if (tid<s){ red[tid]+=red[tid+s]; dred[tid]+=dred[tid+s]; gred[tid]+=gred[tid+s]; }
    __syncthreads();
  }
  if (tid==0){ f[OXS2+n]=red[0]; f[OXD2+n]=dred[0]; f[ORAW3+n]=gred[0]; }
}

// ---- finish: sum 4 head-group partials, elu, dot ep2_w; fused s2 ----
constexpr int TE2 = 16;
__global__ void k_ew2fin(Params P){
  int e0 = blockIdx.x*TE2, g = blockIdx.y, tid = threadIdx.x;
  __shared__ float lred[2][TE2];
  float* f = gf(g);
  float w2 = P.ep2_w[2*OUTD + tid];
  int lane = tid & 63, wvi = tid >> 6;
  for (int e=0;e<TE2;e++){
    const float* src = G_E2PART + ((size_t)g*E + e0 + e)*OUTD + tid;
    float a = 0.f;
    #pragma unroll
    for (int h=0;h<4;h++) a += src[(size_t)h*2*E*OUTD];
    float v = eluf(f[OS1+e0+e]*a) * w2;
    for (int off=32;off>0;off>>=1) v += __shfl_down(v,off);
    if (lane==0) lred[wvi][e]=v;
  }
  __syncthreads();
  if (tid < TE2){
    int e = e0 + tid;
    float ew2 = lred[0][tid]+lred[1][tid];
    const int* ei = P.g[g].eidx;
    int s = ei[e], d = ei[E+e];
    float v = sigmf(f[OXS2+s] + f[OXD2+d] + ew2 + P.ep2_b[0]);
    atomicAdd(&f[OSS2+s], v);
    atomicAdd(&f[ODEG2+s], 1.f);
  }
}

// ---- LSTM input projection ----
__global__ void k_lstm_xg(Params P, int layer){
  int gid = blockIdx.x*4 + (threadIdx.x>>6);
  int lane = threadIdx.x & 63;
  int t = gid >> 10;
  int rem = gid & 1023;
  int d = rem >> 9;
  int gate = rem & 511;
  const float* Wih = layer ? P.Wih1 : P.Wih0;
  const float* bb  = layer ? P.b1   : P.b0;
  const float* xin = layer ? gy0()  : gxseq();
  int Din = layer ? 256 : SEQD;
  const float* x = xin + t*Din;
  const float* Wr = Wih + ((size_t)d*512 + gate)*Din;
  float acc = 0.f;
  for (int k=lane; k<Din; k+=64) acc += x[k]*Wr[k];
  for (int off=32; off>0; off>>=1) acc += __shfl_down(acc, off);
  if (lane==0) gxg()[(t*2 + d)*512 + gate] = acc + bb[d*512 + gate];
}

// ---- LSTM recurrence: coalesced via transposed Whh ----
__global__ void k_lstm_rec(Params P, int layer){
  int d = blockIdx.x, tid = threadIdx.x;
  float* yout = layer ? gy1() : gy0();
  const float* T = G_WHHT + (size_t)(layer*2 + d)*128*512;
  __shared__ float h[128], c[128], gbuf[512];
  if (tid < 128){ h[tid]=0.f; c[tid]=0.f; }
  __syncthreads();
  for (int s=0;s<2;s++){
    int t = (d==0) ? s : 1-s;
    float acc = gxg()[(t*2 + d)*512 + tid];
    for (int k=0;k<128;k++) acc += h[k]*T[(size_t)k*512 + tid];
    gbuf[tid] = acc;
    __syncthreads();
    if (tid < 128){
      float ii = sigmf(gbuf[tid]);
      float ff = sigmf(gbuf[128+tid]);
      float gg = tanhf(gbuf[256+tid]);
      float oo = sigmf(gbuf[384+tid]);
      float cn = ff*c[tid] + ii*gg;
      c[tid] = cn;
      float hn = oo*tanhf(cn);
      h[tid] = hn;
      yout[t*256 + d*128 + tid] = hn;
    }
    __syncthreads();
  }
}

// ---------------- final FC + softmax ----------------
__global__ void k_final(Params P){
  int tid = threadIdx.x;
  __shared__ float sb[256], sb2[256];
  const float* x = gy1() + 256;
  sb[tid]  = x[tid]*P.fc_w[tid*2+0];
  sb2[tid] = x[tid]*P.fc_w[tid*2+1];
  __syncthreads();
  for (int s=128;s>0;s>>=1){ if (tid<s){ sb[tid]+=sb[tid+s]; sb2[tid]+=sb2[tid+s]; } __syncthreads(); }
  if (tid==0){
    float l0 = sb[0] + P.fc_b[0];
    float l1 = sb2[0] + P.fc_b[1];
    float m = fmaxf(l0,l1);
    float e0 = expf(l0-m), e1 = expf(l1-m), inv = 1.f/(e0+e1);
    P.out[0] = e0*inv;
    P.out[1] = e1*inv;
  }
}

extern "C" void kernel_launch(void* const* d_in, const int* in_sizes, int n_in,
                              void* d_out, int out_size, void* d_ws, size_t ws_size,
                              hipStream_t stream){
  Params P;
  for (int g=0; g<2; ++g){
    int b = g*5;
    P.g[g].feat  = (const float*)d_in[b+0];
    P.g[g].eidx  = (const int*)d_in[b+1];
    P.g[g].eattr = (const float*)d_in[b+2];
    P.g[g].adj   = (const float*)d_in[b+3];
    P.g[g].n2n   = (const float*)d_in[b+4];
  }
  P.W_h   = (const float*)d_in[10];
  P.W_gat = (const float*)d_in[11];
  P.a_src = (const float*)d_in[12];
  P.a_dst = (const float*)d_in[13];
  P.a_e   = (const float*)d_in[14];
  P.We_gat= (const float*)d_in[15];
  P.W_out = (const float*)d_in[16];
  P.ao_src= (const float*)d_in[17];
  P.ao_dst= (const float*)d_in[18];
  P.ao_e  = (const float*)d_in[19];
  P.We_out= (const float*)d_in[20];
  P.ep1_w = (const float*)d_in[21];
  P.ep1_b = (const float*)d_in[22];
  P.ep2_w = (const float*)d_in[23];
  P.ep2_b = (const float*)d_in[24];
  P.g1_w  = (const float*)d_in[25];
  P.g1_b  = (const float*)d_in[26];
  P.g2_w  = (const float*)d_in[27];
  P.g2_b  = (const float*)d_in[28];
  P.g3_w  = (const float*)d_in[29];
  P.g3_b  = (const float*)d_in[30];
  P.Wih0  = (const float*)d_in[31];
  P.Whh0  = (const float*)d_in[32];
  P.b0    = (const float*)d_in[33];
  P.Wih1  = (const float*)d_in[34];
  P.Whh1  = (const float*)d_in[35];
  P.b1    = (const float*)d_in[36];
  P.fc_w  = (const float*)d_in[37];
  P.fc_b  = (const float*)d_in[38];
  P.out   = (float*)d_out;

  // ---- graph stages (merged) ----
  k_init <<<dim3(IB_TOT), 256, 0, stream>>>(P);
  k_mega <<<dim3(MB_E2P+MB_ED+MB_WH+MB_PR), 256, 0, stream>>>(P);
  k_att1 <<<dim3(N/4,NH,2),128, 0, stream>>>(P);
  k_xw1  <<<dim3(N,2),    256, 0, stream>>>(P);
  k_s1   <<<dim3((E+255)/256,2), 256, 0, stream>>>(P);
  k_Wh2  <<<dim3(N,2),    512, 0, stream>>>(P);
  k_att2 <<<dim3(N,2),    128, 0, stream>>>(P);
  k_ew2fin<<<dim3(E/TE2,2),128, 0, stream>>>(P);       // +s2
  k_gpools<<<dim3(10),    512, 0, stream>>>(P);        // pool2 + pool3

  // ---- LSTM stack + classifier ----
  k_lstm_xg <<<dim3(512), 256, 0, stream>>>(P, 0);
  k_lstm_rec<<<dim3(2),   512, 0, stream>>>(P, 0);
  k_lstm_xg <<<dim3(512), 256, 0, stream>>>(P, 1);
  k_lstm_rec<<<dim3(2),   512, 0, stream>>>(P, 1);
  k_final<<<dim3(1), 256, 0, stream>>>(P);
}